// Round 1
// 37480.316 us; speedup vs baseline: 1.2781x; 1.2781x over previous
//
#include <hip/hip_runtime.h>
#include <hip/hip_fp16.h>

// RecurrentQNet: B=64, S=1024, D=64, H=512, A=16
// R2: persistent per-batch recurrence kernel.
//   - 64 WGs x 512 threads, one batch per WG, whole 1024-step loop in one launch
//     (eliminates 3072 serialized launches ~ 35-45 ms of launch/drain latency).
//   - Weights converted once to f16 in a lane-interleaved layout (2.55 MB -> fits
//     per-XCD L2 even with 8 WGs/XCD); inner dots use packed __hfma2 (2 MAC/inst)
//     with short f16 chains flushed to fp32 accumulators.
//   - h kept as f32 in registers (thread j owns h[j]) + f16 pairs in LDS; u, inp
//     in LDS; pred passed step-to-step via shuffles into LDS inp buffer.
//   - Epilogue GEMMs (ca1/q) unchanged from R1.

#define B_ 64
#define S_ 1024
#define D_ 64
#define H_ 512
#define A_ 16

#define WG_CHUNKS 240            // per 64-j block: inp 4kb*12 + hh 16kb*12
#define WG_U4     (8 * WG_CHUNKS * 64)   // 122880 uint4
#define WU_U4     (8 * 64 * 64)          // 32768 uint4

union V16 {
    uint4   u;
    float4  f;
    __half2 h[4];
};

// one 32-f16 k-block dot for one gate row: 4 chunks at wp[off + {0,64,128,192}]
__device__ __forceinline__ void dot_block(const uint4* __restrict__ wp, int off,
                                          const V16* __restrict__ a, float& acc) {
    V16 w0, w1, w2, w3;
    w0.u = wp[off];
    w1.u = wp[off + 64];
    w2.u = wp[off + 128];
    w3.u = wp[off + 192];
    __half2 p = __hmul2(w0.h[0], a[0].h[0]);
    __half2 q = __hmul2(w0.h[1], a[0].h[1]);
    p = __hfma2(w0.h[2], a[0].h[2], p);
    q = __hfma2(w0.h[3], a[0].h[3], q);
    p = __hfma2(w1.h[0], a[1].h[0], p);
    q = __hfma2(w1.h[1], a[1].h[1], q);
    p = __hfma2(w1.h[2], a[1].h[2], p);
    q = __hfma2(w1.h[3], a[1].h[3], q);
    p = __hfma2(w2.h[0], a[2].h[0], p);
    q = __hfma2(w2.h[1], a[2].h[1], q);
    p = __hfma2(w2.h[2], a[2].h[2], p);
    q = __hfma2(w2.h[3], a[2].h[3], q);
    p = __hfma2(w3.h[0], a[3].h[0], p);
    q = __hfma2(w3.h[1], a[3].h[1], q);
    p = __hfma2(w3.h[2], a[3].h[2], p);
    q = __hfma2(w3.h[3], a[3].h[3], q);
    float2 fp = __half22float2(p), fq = __half22float2(q);
    acc += (fp.x + fp.y) + (fq.x + fq.y);
}

// ---------------- K0: one-time weight convert + lane-interleave ----------------
// wg layout: uint4 index ((blk*240 + c)*64 + lane), thread j = blk*64+lane.
//   c <  48: inp part,  c = kb*12 + g*4 + q  (kb<4)  src W_ih[g*512+j][kb*32+q*8 ..+7]
//   c >= 48: hh  part,  c-48 = kb*12 + g*4 + q (kb<16) src W_hh[g*512+j][kb*32+q*8 ..+7]
// wu layout: uint4 index ((blk*64 + kb*4 + q)*64 + lane), src cb_w1[j][kb*32+q*8..]
__global__ __launch_bounds__(256) void k_convert(
    const float* __restrict__ W_ih,   // [1536,128]
    const float* __restrict__ W_hh,   // [1536,512]
    const float* __restrict__ cb_w1,  // [512,512]
    uint4* __restrict__ wg, uint4* __restrict__ wu)
{
    int idx = blockIdx.x * 256 + threadIdx.x;
    if (idx < WG_U4) {
        int blk  = idx / (WG_CHUNKS * 64);
        int rem  = idx % (WG_CHUNKS * 64);
        int c    = rem / 64, lane = rem % 64;
        int j    = blk * 64 + lane;
        const float* src;
        if (c < 48) {
            int kb = c / 12, r = c % 12, g = r >> 2, q = r & 3;
            src = W_ih + (size_t)(g * 512 + j) * 128 + kb * 32 + q * 8;
        } else {
            int c2 = c - 48;
            int kb = c2 / 12, r = c2 % 12, g = r >> 2, q = r & 3;
            src = W_hh + (size_t)(g * 512 + j) * 512 + kb * 32 + q * 8;
        }
        V16 o;
#pragma unroll
        for (int i = 0; i < 4; ++i) o.h[i] = __floats2half2_rn(src[2 * i], src[2 * i + 1]);
        wg[idx] = o.u;
    } else if (idx < WG_U4 + WU_U4) {
        int i2   = idx - WG_U4;
        int blk  = i2 / 4096;
        int rem  = i2 % 4096;
        int c    = rem / 64, lane = rem % 64;
        int j    = blk * 64 + lane;
        int kb   = c >> 2, q = c & 3;
        const float* src = cb_w1 + (size_t)j * 512 + kb * 32 + q * 8;
        V16 o;
#pragma unroll
        for (int i = 0; i < 4; ++i) o.h[i] = __floats2half2_rn(src[2 * i], src[2 * i + 1]);
        wu[i2] = o.u;
    }
}

// ---------------- K1: persistent recurrence, one WG per batch ----------------
__global__ __launch_bounds__(512) void k_recur(
    const float* __restrict__ x,      // [64,1024,64]
    const uint4* __restrict__ wg,
    const uint4* __restrict__ wu,
    const float* __restrict__ b_ih,   // [1536]
    const float* __restrict__ b_hh,   // [1536]
    const float* __restrict__ cb_b1,  // [512]
    const float* __restrict__ cb_b2,  // [64]
    const float* __restrict__ cb_w2,  // [64,512] fp32
    float* __restrict__ hist,         // [64,1024,512] (h history = ca1 slot)
    float* __restrict__ hidden,       // [64,512]
    float* __restrict__ cbp)          // [64,1024,64]
{
    __shared__ __align__(16) __half2 s_h2[256];    // h_t as f16 pairs
    __shared__ __align__(16) __half2 s_inp2[64];   // [x_t | pred_{t-1}] as f16 pairs
    __shared__ __align__(16) float   s_u[512];

    const int tid = threadIdx.x;
    const int b   = blockIdx.x;
    const int j   = tid;

    const float bihr = b_ih[j], bihz = b_ih[512 + j], bihn = b_ih[1024 + j];
    const float bhhr = b_hh[j], bhhz = b_hh[512 + j], bhhn = b_hh[1024 + j];
    const float b1j  = cb_b1[j];
    const int   pd   = tid >> 3, psl = tid & 7;
    const float b2d  = cb_b2[pd];
    const float* pw  = cb_w2 + (size_t)pd * 512 + psl * 64;

    float hprev = 0.f;
    if (tid < 256) s_h2[tid] = __floats2half2_rn(0.f, 0.f);
    if (tid < 32) {
        float2 xv = *(const float2*)(x + ((size_t)b * S_) * D_ + tid * 2);
        s_inp2[tid] = __floats2half2_rn(xv.x, xv.y);
    } else if (tid < 64) {
        s_inp2[tid] = __floats2half2_rn(0.f, 0.f);
    }
    __syncthreads();

    const uint4* wgb = wg + (size_t)(tid >> 6) * (WG_CHUNKS * 64) + (tid & 63);
    const uint4* wub = wu + (size_t)(tid >> 6) * (64 * 64) + (tid & 63);

    for (int t = 0; t < S_; ++t) {
        // ---- P1: gates. thread j owns rows {j, 512+j, 1024+j} of (r,z,n) ----
        const uint4* wp = wgb;
        float accr = 0.f, accz = 0.f, accni = 0.f, accnh = 0.f;
        V16 a[4];
#pragma unroll
        for (int kb = 0; kb < 4; ++kb) {          // inp part, K=128
            const float4* ap = (const float4*)s_inp2;
            a[0].f = ap[kb * 4 + 0]; a[1].f = ap[kb * 4 + 1];
            a[2].f = ap[kb * 4 + 2]; a[3].f = ap[kb * 4 + 3];
            dot_block(wp,   0, a, accr);
            dot_block(wp, 256, a, accz);
            dot_block(wp, 512, a, accni);
            wp += 12 * 64;
        }
#pragma unroll 2
        for (int kb = 0; kb < 16; ++kb) {         // hh part, K=512
            const float4* ap = (const float4*)s_h2;
            a[0].f = ap[kb * 4 + 0]; a[1].f = ap[kb * 4 + 1];
            a[2].f = ap[kb * 4 + 2]; a[3].f = ap[kb * 4 + 3];
            dot_block(wp,   0, a, accr);
            dot_block(wp, 256, a, accz);
            dot_block(wp, 512, a, accnh);
            wp += 12 * 64;
        }
        float r = 1.f / (1.f + __expf(-(accr + bihr + bhhr)));
        float z = 1.f / (1.f + __expf(-(accz + bihz + bhhz)));
        float n = tanhf(accni + bihn + r * (accnh + bhhn));
        float hnew = (1.f - z) * n + z * hprev;
        __syncthreads();   // all readers of s_h2/s_inp2 done

        // ---- WB: publish h_t ----
        float oth = __shfl_xor(hnew, 1);
        if (!(tid & 1)) s_h2[tid >> 1] = __floats2half2_rn(hnew, oth);
        hist[((size_t)b * S_ + t) * H_ + j] = hnew;
        if (t == S_ - 1) hidden[(size_t)b * H_ + j] = hnew;
        hprev = hnew;
        __syncthreads();

        // ---- P2: u = relu(cb_w1 @ h_t + b1); also prefetch x_{t+1} pairs ----
        if (tid < 32 && t + 1 < S_) {
            float2 xv = *(const float2*)(x + ((size_t)b * S_ + (t + 1)) * D_ + tid * 2);
            s_inp2[tid] = __floats2half2_rn(xv.x, xv.y);
        }
        const uint4* wp2 = wub;
        float accu = 0.f;
#pragma unroll 2
        for (int kb = 0; kb < 16; ++kb) {
            const float4* ap = (const float4*)s_h2;
            a[0].f = ap[kb * 4 + 0]; a[1].f = ap[kb * 4 + 1];
            a[2].f = ap[kb * 4 + 2]; a[3].f = ap[kb * 4 + 3];
            dot_block(wp2, 0, a, accu);
            wp2 += 256;
        }
        s_u[tid] = fmaxf(accu + b1j, 0.f);
        __syncthreads();

        // ---- P3: pred = cb_w2 @ u + b2 (fp32), 8 lanes per output d ----
        float pa = 0.f;
        const float4* uv = (const float4*)(s_u + psl * 64);
#pragma unroll
        for (int i = 0; i < 16; ++i) {
            float4 uu = uv[i];
            float4 ww = ((const float4*)pw)[i];
            pa += uu.x * ww.x + uu.y * ww.y + uu.z * ww.z + uu.w * ww.w;
        }
        pa += __shfl_xor(pa, 1);
        pa += __shfl_xor(pa, 2);
        pa += __shfl_xor(pa, 4);
        float pv = pa + b2d;
        if (psl == 0) cbp[((size_t)b * S_ + t) * 64 + pd] = pv;
        float po = __shfl_xor(pv, 8);                       // pred of d^1
        if (psl == 0 && !(pd & 1)) s_inp2[32 + (pd >> 1)] = __floats2half2_rn(pv, po);
        __syncthreads();
    }
}

// ---------------- E1: ca1 = relu(h @ fc_w.T + fc_b), IN PLACE (unchanged) ----------------
__global__ __launch_bounds__(256) void k_fc_inplace(
    float* __restrict__ hist,        // in: h rows, out: ca1 rows  [65536,512]
    const float* __restrict__ fc_w,  // [512,512]
    const float* __restrict__ fc_b)  // [512]
{
    __shared__ __align__(16) float s_a[16 * 516];
    const int tid = threadIdx.x;
    const int r = tid & 15;
    const int jset = tid >> 4;
    const int row0 = blockIdx.x * 16;

    for (int i = tid; i < 2048; i += 256) {
        int rr = i >> 7, f = i & 127;
        float4 v = *(const float4*)(hist + (size_t)(row0 + rr) * H_ + f * 4);
        *(float4*)(s_a + rr * 516 + f * 4) = v;
    }
    __syncthreads();

    float acc[32];
#pragma unroll
    for (int jj = 0; jj < 32; ++jj) acc[jj] = 0.f;

    const float4* arow = (const float4*)(s_a + r * 516);
    for (int k4 = 0; k4 < 128; ++k4) {
        float4 a = arow[k4];
#pragma unroll
        for (int jj = 0; jj < 32; ++jj) {
            int j = jset + (jj << 4);
            float4 w = *(const float4*)(fc_w + (size_t)j * 512 + k4 * 4);
            acc[jj] += a.x * w.x + a.y * w.y + a.z * w.z + a.w * w.w;
        }
    }

    float* crow = hist + (size_t)(row0 + r) * H_;
#pragma unroll
    for (int jj = 0; jj < 32; ++jj) {
        int j = jset + (jj << 4);
        float v = acc[jj] + fc_b[j];
        crow[j] = fmaxf(v, 0.f);
    }
}

// ---------------- E3: q = ca1 @ out_w.T + out_b (unchanged) ----------------
__global__ __launch_bounds__(256) void k_q(
    const float* __restrict__ ca1,   // [65536,512]
    const float* __restrict__ out_w, // [16,512]
    const float* __restrict__ out_b, // [16]
    float* __restrict__ q)           // [65536,16]
{
    __shared__ __align__(16) float s_a[16 * 516];
    __shared__ __align__(16) float s_w[16 * 516];
    const int tid = threadIdx.x;
    const int r = tid >> 4;
    const int a_ = tid & 15;
    const int row0 = blockIdx.x * 16;

    for (int i = tid; i < 2048; i += 256) {
        int rr = i >> 7, f = i & 127;
        float4 v = *(const float4*)(ca1 + (size_t)(row0 + rr) * H_ + f * 4);
        *(float4*)(s_a + rr * 516 + f * 4) = v;
    }
    for (int i = tid; i < 2048; i += 256) {
        int rr = i >> 7, f = i & 127;
        float4 v = *(const float4*)(out_w + (size_t)rr * 512 + f * 4);
        *(float4*)(s_w + rr * 516 + f * 4) = v;
    }
    __syncthreads();

    const float4* arow = (const float4*)(s_a + r * 516);
    const float4* wrow = (const float4*)(s_w + a_ * 516);
    float acc = 0.f;
#pragma unroll 8
    for (int k4 = 0; k4 < 128; ++k4) {
        float4 a = arow[k4];
        float4 w = wrow[k4];
        acc += a.x * w.x + a.y * w.y + a.z * w.z + a.w * w.w;
    }
    q[(size_t)(row0 + r) * A_ + a_] = acc + out_b[a_];
}

// ---------------- host ----------------
extern "C" void kernel_launch(void* const* d_in, const int* in_sizes, int n_in,
                              void* d_out, int out_size, void* d_ws, size_t ws_size,
                              hipStream_t stream) {
    const float* x     = (const float*)d_in[0];
    const float* W_ih  = (const float*)d_in[1];
    const float* W_hh  = (const float*)d_in[2];
    const float* b_ih  = (const float*)d_in[3];
    const float* b_hh  = (const float*)d_in[4];
    const float* fc_w  = (const float*)d_in[5];
    const float* fc_b  = (const float*)d_in[6];
    const float* out_w = (const float*)d_in[7];
    const float* out_b = (const float*)d_in[8];
    const float* cb_w1 = (const float*)d_in[9];
    const float* cb_b1 = (const float*)d_in[10];
    const float* cb_w2 = (const float*)d_in[11];
    const float* cb_b2 = (const float*)d_in[12];

    float* q_out  = (float*)d_out;                     // [64,1024,16]
    float* cbp    = q_out + (size_t)B_ * S_ * A_;      // [64,1024,64]
    float* hidden = cbp + (size_t)B_ * S_ * D_;        // [1,64,512]
    float* ca1    = hidden + (size_t)B_ * H_;          // [64,1024,512] (h-history then ca1)

    uint4* wg = (uint4*)d_ws;                          // 122880 uint4 = 1.875 MB
    uint4* wu = wg + WG_U4;                            // 32768 uint4 = 0.5 MB

    k_convert<<<(WG_U4 + WU_U4) / 256, 256, 0, stream>>>(W_ih, W_hh, cb_w1, wg, wu);
    k_recur<<<B_, 512, 0, stream>>>(x, wg, wu, b_ih, b_hh, cb_b1, cb_b2, cb_w2,
                                    ca1, hidden, cbp);
    k_fc_inplace<<<4096, 256, 0, stream>>>(ca1, fc_w, fc_b);
    k_q<<<4096, 256, 0, stream>>>(ca1, out_w, out_b, q_out);
}